// Round 1
// baseline (631.763 us; speedup 1.0000x reference)
//
#include <hip/hip_runtime.h>
#include <hip/hip_bf16.h>

#define RANK  200
#define N_ENT 200000
#define N_REL 500
#define NNZ   500000

// Phase 1: find, per entity/relation row, the winning nnz index under
// numpy scatter-set semantics:
//   grad_a[subj] = g_a  (pass 1, last duplicate index wins)
//   grad_a[obj]  = g_c  (pass 2, overwrites pass 1 rows)
// Encode winner key: subj write at nnz i -> key i; obj write -> key NNZ+i.
// Any obj key beats any subj key; within a class, larger i wins. atomicMax.
__global__ void winner_kernel(const int* __restrict__ coo,
                              int* __restrict__ wA, int* __restrict__ wB) {
    int i = blockIdx.x * blockDim.x + threadIdx.x;
    if (i >= NNZ) return;
    int s = coo[3 * i + 0];
    int r = coo[3 * i + 1];
    int o = coo[3 * i + 2];
    atomicMax(&wA[s], i);
    atomicMax(&wA[o], NNZ + i);
    atomicMax(&wB[r], i);
}

// Phase 2: per-nnz loss + stash diff. One 64-lane wave per nnz;
// cooperative coalesced dot over RANK=200, butterfly shuffle reduce.
__global__ void loss_kernel(const int* __restrict__ coo,
                            const float* __restrict__ vals,
                            const float* __restrict__ a,
                            const float* __restrict__ b,
                            float* __restrict__ loss,
                            float* __restrict__ diff) {
    int wave = (blockIdx.x * blockDim.x + threadIdx.x) >> 6;
    int lane = threadIdx.x & 63;
    if (wave >= NNZ) return;
    int s = coo[3 * wave + 0];
    int r = coo[3 * wave + 1];
    int o = coo[3 * wave + 2];
    const float* __restrict__ as_ = a + (long long)s * RANK;
    const float* __restrict__ br_ = b + (long long)r * RANK;
    const float* __restrict__ ao_ = a + (long long)o * RANK;
    float sum = 0.0f;
    #pragma unroll
    for (int k = lane; k < RANK; k += 64)
        sum += as_[k] * br_[k] * ao_[k];
    #pragma unroll
    for (int off = 32; off > 0; off >>= 1)
        sum += __shfl_down(sum, off, 64);
    if (lane == 0) {
        float d = sum - vals[wave];
        loss[wave] = d * d;
        diff[wave] = d;
    }
}

// Phase 3: one wave per output row. Rows [0, N_ENT) -> grad_a,
// rows [N_ENT, N_ENT+N_REL) -> grad_b. Untouched rows get zeros
// (harness poisons d_out, so every element must be written).
__global__ void grad_kernel(const int* __restrict__ coo,
                            const float* __restrict__ diff,
                            const float* __restrict__ a,
                            const float* __restrict__ b,
                            const int* __restrict__ wA,
                            const int* __restrict__ wB,
                            float* __restrict__ grad_a,
                            float* __restrict__ grad_b) {
    int row  = (blockIdx.x * blockDim.x + threadIdx.x) >> 6;
    int lane = threadIdx.x & 63;
    if (row < N_ENT) {
        int key = wA[row];
        float* __restrict__ out = grad_a + (long long)row * RANK;
        if (key < 0) {
            #pragma unroll
            for (int j = lane; j < RANK; j += 64) out[j] = 0.0f;
            return;
        }
        bool is_obj = key >= NNZ;
        int i = is_obj ? (key - NNZ) : key;
        int s = coo[3 * i + 0];
        int r = coo[3 * i + 1];
        int o = coo[3 * i + 2];
        float d = 2.0f * diff[i];
        // subj winner: g_a = d * b1 * a2 ; obj winner: g_c = d * a0 * b1
        const float* __restrict__ x = b + (long long)r * RANK;
        const float* __restrict__ y = is_obj ? (a + (long long)s * RANK)
                                             : (a + (long long)o * RANK);
        #pragma unroll
        for (int j = lane; j < RANK; j += 64) out[j] = d * x[j] * y[j];
    } else if (row < N_ENT + N_REL) {
        int rr = row - N_ENT;
        int key = wB[rr];
        float* __restrict__ out = grad_b + (long long)rr * RANK;
        if (key < 0) {
            #pragma unroll
            for (int j = lane; j < RANK; j += 64) out[j] = 0.0f;
            return;
        }
        int s = coo[3 * key + 0];
        int o = coo[3 * key + 2];
        float d = 2.0f * diff[key];
        // g_b = d * a0 * a2
        const float* __restrict__ x = a + (long long)s * RANK;
        const float* __restrict__ y = a + (long long)o * RANK;
        #pragma unroll
        for (int j = lane; j < RANK; j += 64) out[j] = d * x[j] * y[j];
    }
}

extern "C" void kernel_launch(void* const* d_in, const int* in_sizes, int n_in,
                              void* d_out, int out_size, void* d_ws, size_t ws_size,
                              hipStream_t stream) {
    const int*   coo  = (const int*)d_in[0];    // (NNZ, 3) int32
    const float* vals = (const float*)d_in[1];  // (NNZ,)   fp32
    const float* a    = (const float*)d_in[2];  // (N_ENT, RANK)
    const float* b    = (const float*)d_in[3];  // (N_REL, RANK)

    float* loss   = (float*)d_out;                       // NNZ
    float* grad_a = loss + NNZ;                          // N_ENT*RANK
    float* grad_b = grad_a + (size_t)N_ENT * RANK;       // N_REL*RANK

    float* diff = (float*)d_ws;                          // NNZ floats
    int*   wA   = (int*)(diff + NNZ);                    // N_ENT ints
    int*   wB   = wA + N_ENT;                            // N_REL ints

    // winners init to -1 (0xFF bytes)
    hipMemsetAsync(wA, 0xFF, (size_t)(N_ENT + N_REL) * sizeof(int), stream);

    {
        int threads = 256;
        int blocks = (NNZ + threads - 1) / threads;
        winner_kernel<<<blocks, threads, 0, stream>>>(coo, wA, wB);
    }
    {
        long long total = (long long)NNZ * 64;
        int threads = 256;
        long long blocks = (total + threads - 1) / threads;
        loss_kernel<<<(int)blocks, threads, 0, stream>>>(coo, vals, a, b, loss, diff);
    }
    {
        long long total = (long long)(N_ENT + N_REL) * 64;
        int threads = 256;
        long long blocks = (total + threads - 1) / threads;
        grad_kernel<<<(int)blocks, threads, 0, stream>>>(coo, diff, a, b, wA, wB,
                                                         grad_a, grad_b);
    }
}

// Round 2
// 481.053 us; speedup vs baseline: 1.3133x; 1.3133x over previous
//
#include <hip/hip_runtime.h>
#include <hip/hip_bf16.h>

#define RANK   200
#define N_ENT  200000
#define N_REL  500
#define NNZ    500000
#define NB_WIN 256          // blocks in winner stage-1
#define WB_PAD 512          // padded relation slots per partial row

// ---------------------------------------------------------------------------
// Winner semantics (numpy scatter-SET, last write wins):
//   grad_a[subj] = g_a  (pass 1)   then   grad_a[obj] = g_c  (pass 2 overwrites)
// Key encoding for wA: subj write at nnz i -> i ; obj write -> NNZ+i.
// wB winner = max nnz index per relation.
// wB has only 500 ints (32 cachelines) -> global atomics serialize (~189us).
// Instead: per-block LDS max + plain-store partials, then a tiny reduce kernel.
// ---------------------------------------------------------------------------
__global__ void winner_kernel(const int* __restrict__ coo,
                              int* __restrict__ wA,
                              int* __restrict__ partial_wB) {
    __shared__ int lwB[WB_PAD];
    for (int t = threadIdx.x; t < WB_PAD; t += blockDim.x) lwB[t] = -1;
    __syncthreads();

    int gtid   = blockIdx.x * blockDim.x + threadIdx.x;
    int stride = gridDim.x * blockDim.x;
    for (int i = gtid; i < NNZ; i += stride) {
        int s = coo[3 * i + 0];
        int r = coo[3 * i + 1];
        int o = coo[3 * i + 2];
        atomicMax(&wA[s], i);           // light contention: ~5 per address
        atomicMax(&wA[o], NNZ + i);
        atomicMax(&lwB[r], i);          // LDS atomic, per-CU
    }
    __syncthreads();
    int* out = partial_wB + (size_t)blockIdx.x * WB_PAD;
    for (int t = threadIdx.x; t < WB_PAD; t += blockDim.x) out[t] = lwB[t];
}

__global__ void wb_reduce_kernel(const int* __restrict__ partial_wB,
                                 int* __restrict__ wB) {
    int t = threadIdx.x;                // single block of WB_PAD threads
    int m = -1;
    for (int nb = 0; nb < NB_WIN; ++nb)
        m = max(m, partial_wB[(size_t)nb * WB_PAD + t]);
    if (t < N_REL) wB[t] = m;
}

// ---------------------------------------------------------------------------
// Loss: one 64-lane wave per nnz. Rows are 800 B = 50 x float4 (16B aligned):
// lanes 0-49 each load one float4 from each of the 3 rows -> one transaction
// per row. Butterfly shuffle reduce across 64 lanes (lanes 50-63 hold 0).
// ---------------------------------------------------------------------------
__global__ void loss_kernel(const int* __restrict__ coo,
                            const float* __restrict__ vals,
                            const float* __restrict__ a,
                            const float* __restrict__ b,
                            float* __restrict__ loss,
                            float* __restrict__ diff) {
    int wave = (blockIdx.x * blockDim.x + threadIdx.x) >> 6;
    int lane = threadIdx.x & 63;
    if (wave >= NNZ) return;
    int s = coo[3 * wave + 0];
    int r = coo[3 * wave + 1];
    int o = coo[3 * wave + 2];
    float sum = 0.0f;
    if (lane < RANK / 4) {
        const float4* as_ = (const float4*)(a + (size_t)s * RANK) + lane;
        const float4* br_ = (const float4*)(b + (size_t)r * RANK) + lane;
        const float4* ao_ = (const float4*)(a + (size_t)o * RANK) + lane;
        float4 x = *as_, y = *br_, z = *ao_;
        sum = x.x * y.x * z.x + x.y * y.y * z.y
            + x.z * y.z * z.z + x.w * y.w * z.w;
    }
    #pragma unroll
    for (int off = 32; off > 0; off >>= 1)
        sum += __shfl_down(sum, off, 64);
    if (lane == 0) {
        float d = sum - vals[wave];
        loss[wave] = d * d;
        diff[wave] = d;
    }
}

// ---------------------------------------------------------------------------
// Grad: one wave per output row; lanes 0-49 write one float4 each (whole
// 800 B row in one transaction). Untouched rows -> zeros (d_out is poisoned).
// ---------------------------------------------------------------------------
__global__ void grad_kernel(const int* __restrict__ coo,
                            const float* __restrict__ diff,
                            const float* __restrict__ a,
                            const float* __restrict__ b,
                            const int* __restrict__ wA,
                            const int* __restrict__ wB,
                            float* __restrict__ grad_a,
                            float* __restrict__ grad_b) {
    int row  = (blockIdx.x * blockDim.x + threadIdx.x) >> 6;
    int lane = threadIdx.x & 63;
    if (row >= N_ENT + N_REL) return;

    const float *x, *y;
    float d = 0.0f;
    float4* out;
    if (row < N_ENT) {
        out = (float4*)(grad_a + (size_t)row * RANK);
        int key = wA[row];
        if (key < 0) {
            if (lane < RANK / 4) out[lane] = make_float4(0.f, 0.f, 0.f, 0.f);
            return;
        }
        bool is_obj = key >= NNZ;
        int i = is_obj ? (key - NNZ) : key;
        int s = coo[3 * i + 0];
        int r = coo[3 * i + 1];
        int o = coo[3 * i + 2];
        d = 2.0f * diff[i];
        x = b + (size_t)r * RANK;                       // both cases use b1
        y = is_obj ? (a + (size_t)s * RANK)             // g_c = d*a0*b1
                   : (a + (size_t)o * RANK);            // g_a = d*b1*a2
    } else {
        int rr = row - N_ENT;
        out = (float4*)(grad_b + (size_t)rr * RANK);
        int key = wB[rr];
        if (key < 0) {
            if (lane < RANK / 4) out[lane] = make_float4(0.f, 0.f, 0.f, 0.f);
            return;
        }
        int s = coo[3 * key + 0];
        int o = coo[3 * key + 2];
        d = 2.0f * diff[key];
        x = a + (size_t)s * RANK;                       // g_b = d*a0*a2
        y = a + (size_t)o * RANK;
    }
    if (lane < RANK / 4) {
        float4 xv = ((const float4*)x)[lane];
        float4 yv = ((const float4*)y)[lane];
        out[lane] = make_float4(d * xv.x * yv.x, d * xv.y * yv.y,
                                d * xv.z * yv.z, d * xv.w * yv.w);
    }
}

extern "C" void kernel_launch(void* const* d_in, const int* in_sizes, int n_in,
                              void* d_out, int out_size, void* d_ws, size_t ws_size,
                              hipStream_t stream) {
    const int*   coo  = (const int*)d_in[0];    // (NNZ, 3) int32
    const float* vals = (const float*)d_in[1];  // (NNZ,)   fp32
    const float* a    = (const float*)d_in[2];  // (N_ENT, RANK)
    const float* b    = (const float*)d_in[3];  // (N_REL, RANK)

    float* loss   = (float*)d_out;                       // NNZ
    float* grad_a = loss + NNZ;                          // N_ENT*RANK
    float* grad_b = grad_a + (size_t)N_ENT * RANK;       // N_REL*RANK

    float* diff       = (float*)d_ws;                    // NNZ floats
    int*   wA         = (int*)(diff + NNZ);              // N_ENT ints
    int*   wB         = wA + N_ENT;                      // WB_PAD ints
    int*   partial_wB = wB + WB_PAD;                     // NB_WIN*WB_PAD ints

    // wA init to -1 (0xFF bytes); wB / partial_wB are fully overwritten.
    hipMemsetAsync(wA, 0xFF, (size_t)N_ENT * sizeof(int), stream);

    winner_kernel<<<NB_WIN, 256, 0, stream>>>(coo, wA, partial_wB);
    wb_reduce_kernel<<<1, WB_PAD, 0, stream>>>(partial_wB, wB);
    {
        long long total = (long long)NNZ * 64;
        int threads = 256;
        long long blocks = (total + threads - 1) / threads;
        loss_kernel<<<(int)blocks, threads, 0, stream>>>(coo, vals, a, b, loss, diff);
    }
    {
        long long total = (long long)(N_ENT + N_REL) * 64;
        int threads = 256;
        long long blocks = (total + threads - 1) / threads;
        grad_kernel<<<(int)blocks, threads, 0, stream>>>(coo, diff, a, b, wA, wB,
                                                         grad_a, grad_b);
    }
}